// Round 5
// baseline (626.620 us; speedup 1.0000x reference)
//
#include <hip/hip_runtime.h>
#include <hip/hip_bf16.h>

#define NPTS 16384
#define DIM  2048
#define NGRP 4096
#define BK   32
#define NT   (DIM / BK)   // 64 K-tiles

typedef __bf16 bf16x8 __attribute__((ext_vector_type(8)));
typedef unsigned short u16x8 __attribute__((ext_vector_type(8)));
typedef float f32x4 __attribute__((ext_vector_type(4)));

__device__ __forceinline__ unsigned short f2bf(float f) {
  union { float f; unsigned u; } v; v.f = f;
  unsigned u = v.u;
  return (unsigned short)((u + 0x7FFFu + ((u >> 16) & 1u)) >> 16);  // RTNE
}
__device__ __forceinline__ float bflo(unsigned u) { return __uint_as_float(u << 16); }
__device__ __forceinline__ float bfhi(unsigned u) { return __uint_as_float(u & 0xffff0000u); }

// Async global->LDS, 16B per lane. LDS dest is wave-uniform base + lane*16.
__device__ __forceinline__ void gload16(const void* g, void* lds) {
  __builtin_amdgcn_global_load_lds(
      (const __attribute__((address_space(1))) unsigned*)g,
      (__attribute__((address_space(3))) unsigned*)lds, 16, 0, 0);
}

// Per-wave deterministic dtype sniff: all waves inspect X[0..63] -> identical verdict.
__device__ __forceinline__ bool sniff_bf16(const void* X) {
  const int lane = threadIdx.x & 63;
  unsigned hb = (((const unsigned short*)X)[lane] >> 8) & 0x7Fu;
  unsigned long long m = __ballot(hb >= 0x3Bu && hb <= 0x41u);
  return __popcll(m) >= 48;
}

// ---- fused prep: self-sniff + row norms (+ fp32->bf16 copy when fp32 input) ----
__global__ __launch_bounds__(256) void prep_all_kernel(
    const void* __restrict__ Xin, const void* __restrict__ Ein,
    unsigned short* __restrict__ Xbf, unsigned short* __restrict__ Ebf,
    float* __restrict__ x2, float* __restrict__ e2) {
  const int lane  = threadIdx.x & 63;
  const int wavei = threadIdx.x >> 6;
  const bool isbf = sniff_bf16(Xin);

  const int grow = blockIdx.x * 4 + wavei;
  const void* in; unsigned short* q; float* nrm; int row;
  if (grow < NPTS) { in = Xin; q = Xbf; nrm = x2; row = grow; }
  else             { in = Ein; q = Ebf; nrm = e2; row = grow - NPTS; }

  float s = 0.f;
  if (isbf) {
    const unsigned short* p = (const unsigned short*)in + (size_t)row * DIM;
#pragma unroll
    for (int it = 0; it < 4; ++it) {
      uint4 v = *(const uint4*)(p + it * 512 + lane * 8);
      float f;
      f = bflo(v.x); s += f * f;  f = bfhi(v.x); s += f * f;
      f = bflo(v.y); s += f * f;  f = bfhi(v.y); s += f * f;
      f = bflo(v.z); s += f * f;  f = bfhi(v.z); s += f * f;
      f = bflo(v.w); s += f * f;  f = bfhi(v.w); s += f * f;
    }
  } else {
    const float* p = (const float*)in + (size_t)row * DIM;
    unsigned short* qq = q + (size_t)row * DIM;
#pragma unroll
    for (int it = 0; it < 4; ++it) {
      float4 a = *(const float4*)(p + it * 512 + lane * 8);
      float4 b = *(const float4*)(p + it * 512 + lane * 8 + 4);
      s += a.x * a.x + a.y * a.y + a.z * a.z + a.w * a.w;
      s += b.x * b.x + b.y * b.y + b.z * b.z + b.w * b.w;
      u16x8 r;
      r[0] = f2bf(a.x); r[1] = f2bf(a.y); r[2] = f2bf(a.z); r[3] = f2bf(a.w);
      r[4] = f2bf(b.x); r[5] = f2bf(b.y); r[6] = f2bf(b.z); r[7] = f2bf(b.w);
      *(u16x8*)(qq + it * 512 + lane * 8) = r;
    }
  }
#pragma unroll
  for (int off = 32; off > 0; off >>= 1) s += __shfl_down(s, off, 64);
  if (lane == 0) nrm[row] = s;
}

// ---- 256x256 8-wave GEMM, BK=32, 4-deep circular LDS (128 KiB).
//      Cross-barrier pipelined fragment reads: ds_reads issue one phase early,
//      lgkmcnt(0)-waited after the barrier (rule #18: + sched_barrier(0)).
//      Counted vmcnt (8 in main loop, 8->4->0 tail), 2 raw barriers/tile,
//      setprio around MFMA clusters. Plain 2D grid (R3 config; R4 XCD remap
//      reverted: FETCH fell but time rose -> L3-resident, not HBM-bound). ----
#define A_OFF 0
#define B_OFF 8192

__global__ __launch_bounds__(512, 2) void gemm_8p_kernel(
    const void* __restrict__ Xin, const unsigned short* __restrict__ Xws,
    const void* __restrict__ Ein, const unsigned short* __restrict__ Ews,
    const float* __restrict__ x2, const float* __restrict__ e2,
    void* __restrict__ outv) {
  // 4 bufs x [ A: 256x32 | B: 256x32 ] bf16 = 4 x 32 KiB = 128 KiB
  __shared__ __align__(16) unsigned short sbuf[4][16384];

  const int tid  = threadIdx.x;
  const int lane = tid & 63;
  const int wave = tid >> 6;   // 0..7
  const int wm   = wave >> 2;  // 0..1  (M half: 128 rows)
  const int wn   = wave & 3;   // 0..3  (N quarter: 64 cols)
  const int quad = lane >> 4;
  const int l16  = lane & 15;

  const bool isbf = sniff_bf16(Xin);
  const unsigned short* X = isbf ? (const unsigned short*)Xin : Xws;
  const unsigned short* E = isbf ? (const unsigned short*)Ein : Ews;

  const int rowBase = blockIdx.y * 256;
  const int colBase = blockIdx.x * 256;

  // Staging: one gload16 moves one 128x32 half-tile (512 thr x 8 elem).
  const int srow = tid >> 2;          // 0..127
  const int scol = (tid & 3) * 8;     // 0,8,16,24
  const size_t gA = (size_t)(rowBase + srow) * DIM + scol;
  const size_t gB = (size_t)(colBase + srow) * DIM + scol;
  const size_t HSTRIDE = (size_t)128 * DIM;

  // Fragment offsets (elements). A frag mt: row = wm*128 + mt*16 + l16, k = quad*8.
  // Reads are fully contiguous 1KB per wave per frag -> conflict-free at BK=32.
  const int aoff = (wm * 128 + l16) * 32 + quad * 8;          // + mt*512
  const int boff = B_OFF + (wn * 64 + l16) * 32 + quad * 8;   // + nt*512

  f32x4 zero = {0.f, 0.f, 0.f, 0.f};
  f32x4 acc[8][4];
#pragma unroll
  for (int mt = 0; mt < 8; ++mt)
#pragma unroll
    for (int nt = 0; nt < 4; ++nt) acc[mt][nt] = zero;

  bf16x8 aL[4], aH[4], bF[4];

#define STAGE_A(t_) do { const size_t k_ = (size_t)(t_) * BK;                         \
    gload16(X + gA + k_,           &sbuf[(t_) & 3][A_OFF + wave * 512]);              \
    gload16(X + gA + HSTRIDE + k_, &sbuf[(t_) & 3][A_OFF + 4096 + wave * 512]);       \
  } while (0)
#define STAGE_B(t_) do { const size_t k_ = (size_t)(t_) * BK;                         \
    gload16(E + gB + k_,           &sbuf[(t_) & 3][B_OFF + wave * 512]);              \
    gload16(E + gB + HSTRIDE + k_, &sbuf[(t_) & 3][B_OFF + 4096 + wave * 512]);       \
  } while (0)

#define DSR_L(t_) do { const unsigned short* sb_ = sbuf[(t_) & 3];                    \
    _Pragma("unroll") for (int mt = 0; mt < 4; ++mt)                                  \
      aL[mt] = *(const bf16x8*)(const void*)(sb_ + aoff + mt * 512);                  \
    _Pragma("unroll") for (int nt = 0; nt < 4; ++nt)                                  \
      bF[nt] = *(const bf16x8*)(const void*)(sb_ + boff + nt * 512);                  \
  } while (0)
#define DSR_H(t_) do { const unsigned short* sb_ = sbuf[(t_) & 3];                    \
    _Pragma("unroll") for (int mt = 0; mt < 4; ++mt)                                  \
      aH[mt] = *(const bf16x8*)(const void*)(sb_ + aoff + (mt + 4) * 512);            \
  } while (0)

  // Body invariant at entry: tile t resident + barrier'd; DSR_L(t) reads IN
  // FLIGHT; own vmcnt in-flight = 8 (tiles t+1, t+2).
  // Race audit: STAGE_A(t+3) writes buf[(t-1)&3]; every wave completed its
  // aH(t-1) reads at its pre-P1 lgkmcnt(0), before the end-of-tile barrier of
  // t-1, which precedes this. DSR_L(t+1) only after vmcnt(8)+barrier pair.
#define BODY(t_, DOSTAGE_, VMN_, DONEXT_) do {                                        \
    if (DOSTAGE_) STAGE_A((t_) + 3);                                                  \
    asm volatile("s_waitcnt lgkmcnt(0)" ::: "memory");                                \
    __builtin_amdgcn_sched_barrier(0);                                                \
    DSR_H(t_);                                                                        \
    __builtin_amdgcn_sched_barrier(0);                                                \
    __builtin_amdgcn_s_setprio(1);                                                    \
    _Pragma("unroll") for (int mt = 0; mt < 4; ++mt)                                  \
      _Pragma("unroll") for (int nt = 0; nt < 4; ++nt)                                \
        acc[mt][nt] = __builtin_amdgcn_mfma_f32_16x16x32_bf16(aL[mt], bF[nt],         \
                                                              acc[mt][nt], 0, 0, 0);  \
    __builtin_amdgcn_s_setprio(0);                                                    \
    if (DOSTAGE_) STAGE_B((t_) + 3);                                                  \
    __builtin_amdgcn_s_barrier();                                                     \
    asm volatile("s_waitcnt lgkmcnt(0)" ::: "memory");                                \
    __builtin_amdgcn_sched_barrier(0);                                                \
    __builtin_amdgcn_s_setprio(1);                                                    \
    _Pragma("unroll") for (int mt = 0; mt < 4; ++mt)                                  \
      _Pragma("unroll") for (int nt = 0; nt < 4; ++nt)                                \
        acc[mt + 4][nt] = __builtin_amdgcn_mfma_f32_16x16x32_bf16(aH[mt], bF[nt],     \
                                                              acc[mt + 4][nt], 0, 0, 0); \
    __builtin_amdgcn_s_setprio(0);                                                    \
    asm volatile("s_waitcnt vmcnt(" #VMN_ ")" ::: "memory");                          \
    __builtin_amdgcn_s_barrier();                                                     \
    __builtin_amdgcn_sched_barrier(0);                                                \
    if (DONEXT_) { DSR_L((t_) + 1); __builtin_amdgcn_sched_barrier(0); }              \
  } while (0)

  // Prologue: 3 K-tiles in flight (12 loads/thread); tile 0 resident; issue
  // tile-0 fragment reads (they complete under BODY(0)'s entry wait).
  STAGE_A(0); STAGE_B(0);
  STAGE_A(1); STAGE_B(1);
  STAGE_A(2); STAGE_B(2);
  asm volatile("s_waitcnt vmcnt(8)" ::: "memory");
  __builtin_amdgcn_s_barrier();
  __builtin_amdgcn_sched_barrier(0);
  DSR_L(0);
  __builtin_amdgcn_sched_barrier(0);

#pragma unroll 1
  for (int t = 0; t < NT - 3; ++t) {
    BODY(t, true, 8, true);
  }
  // Tail drain: 8 -> 4 -> 0.
  BODY(NT - 3, false, 4, true);
  BODY(NT - 2, false, 0, true);
  BODY(NT - 1, false, 0, false);
#undef BODY
#undef DSR_L
#undef DSR_H
#undef STAGE_A
#undef STAGE_B

  // Epilogue. C/D layout: col = lane&15, row = quad*4 + reg [m89/m91].
  float ec[4];
#pragma unroll
  for (int nt = 0; nt < 4; ++nt) ec[nt] = e2[colBase + wn * 64 + nt * 16 + l16];

  if (isbf) {
    unsigned short* out = (unsigned short*)outv;
#pragma unroll
    for (int mt = 0; mt < 8; ++mt)
#pragma unroll
      for (int r2 = 0; r2 < 4; ++r2) {
        const int row = rowBase + wm * 128 + mt * 16 + quad * 4 + r2;
        const float xr = x2[row];
#pragma unroll
        for (int nt = 0; nt < 4; ++nt) {
          const int col = colBase + wn * 64 + nt * 16 + l16;
          float sq = xr + ec[nt] - 2.0f * acc[mt][nt][r2];
          sq = sq > 0.f ? sq : 0.f;
          out[(size_t)row * NGRP + col] = f2bf(-__builtin_sqrtf(sq));
        }
      }
  } else {
    float* out = (float*)outv;
#pragma unroll
    for (int mt = 0; mt < 8; ++mt)
#pragma unroll
      for (int r2 = 0; r2 < 4; ++r2) {
        const int row = rowBase + wm * 128 + mt * 16 + quad * 4 + r2;
        const float xr = x2[row];
#pragma unroll
        for (int nt = 0; nt < 4; ++nt) {
          const int col = colBase + wn * 64 + nt * 16 + l16;
          float sq = xr + ec[nt] - 2.0f * acc[mt][nt][r2];
          sq = sq > 0.f ? sq : 0.f;
          out[(size_t)row * NGRP + col] = -__builtin_sqrtf(sq);
        }
      }
  }
}

// ---------------- fallback path (workspace too small): round-0 kernels ----------------

__global__ void sniff_kernel(const unsigned short* __restrict__ X, int* __restrict__ flag) {
  if (threadIdx.x == 0 && blockIdx.x == 0) {
    int c = 0;
    for (int i = 0; i < 64; ++i) {
      unsigned b = (X[i] >> 8) & 0x7F;
      c += (b >= 0x3B && b <= 0x41) ? 1 : 0;
    }
    *flag = (c >= 48) ? 1 : 0;
  }
}

__global__ __launch_bounds__(256) void rownorm_kernel(const void* __restrict__ in,
                                                      float* __restrict__ out,
                                                      const int* __restrict__ flag) {
  const int wave = threadIdx.x >> 6;
  const int lane = threadIdx.x & 63;
  const int row  = blockIdx.x * 4 + wave;
  float s = 0.f;
  if (*flag) {
    const unsigned short* p = (const unsigned short*)in + (size_t)row * DIM;
#pragma unroll
    for (int it = 0; it < 4; ++it) {
      uint4 v = *(const uint4*)(p + it * 512 + lane * 8);
      float f;
      f = bflo(v.x); s += f * f;  f = bfhi(v.x); s += f * f;
      f = bflo(v.y); s += f * f;  f = bfhi(v.y); s += f * f;
      f = bflo(v.z); s += f * f;  f = bfhi(v.z); s += f * f;
      f = bflo(v.w); s += f * f;  f = bfhi(v.w); s += f * f;
    }
  } else {
    const float* p = (const float*)in + (size_t)row * DIM;
#pragma unroll
    for (int it = 0; it < 4; ++it) {
      float4 a = *(const float4*)(p + it * 512 + lane * 8);
      float4 b = *(const float4*)(p + it * 512 + lane * 8 + 4);
      s += a.x * a.x + a.y * a.y + a.z * a.z + a.w * a.w;
      s += b.x * b.x + b.y * b.y + b.z * b.z + b.w * b.w;
    }
  }
#pragma unroll
  for (int off = 32; off > 0; off >>= 1) s += __shfl_down(s, off, 64);
  if (lane == 0) out[row] = s;
}

__device__ __forceinline__ u16x8 cvt8(const float* p) {
  float4 a = *(const float4*)p;
  float4 b = *(const float4*)(p + 4);
  u16x8 r;
  r[0] = f2bf(a.x); r[1] = f2bf(a.y); r[2] = f2bf(a.z); r[3] = f2bf(a.w);
  r[4] = f2bf(b.x); r[5] = f2bf(b.y); r[6] = f2bf(b.z); r[7] = f2bf(b.w);
  return r;
}

__global__ __launch_bounds__(256) void gemm_dist_kernel(
    const void* __restrict__ Xv, const void* __restrict__ Ev,
    const float* __restrict__ x2, const float* __restrict__ e2,
    void* __restrict__ outv, const int* __restrict__ flag) {
  __shared__ __align__(16) unsigned short sA[128 * 32];
  __shared__ __align__(16) unsigned short sB[128 * 32];

  const bool isbf = (*flag != 0);
  const int tid  = threadIdx.x;
  const int lane = tid & 63;
  const int wave = tid >> 6;
  const int wm   = wave >> 1;
  const int wn   = wave & 1;
  const int quad = lane >> 4;
  const int l16  = lane & 15;

  const int rowBase = blockIdx.y * 128;
  const int colBase = blockIdx.x * 128;

  const int flat0 = tid * 8;
  const int flat1 = (tid + 256) * 8;
  const int r0 = flat0 >> 5, c0 = flat0 & 31;
  const int r1 = flat1 >> 5, c1 = flat1 & 31;

  const size_t iA0 = (size_t)(rowBase + r0) * DIM + c0;
  const size_t iA1 = (size_t)(rowBase + r1) * DIM + c1;
  const size_t iB0 = (size_t)(colBase + r0) * DIM + c0;
  const size_t iB1 = (size_t)(colBase + r1) * DIM + c1;

  f32x4 zero = {0.f, 0.f, 0.f, 0.f};
  f32x4 acc[4][4];
#pragma unroll
  for (int mt = 0; mt < 4; ++mt)
#pragma unroll
    for (int nt = 0; nt < 4; ++nt) acc[mt][nt] = zero;

  for (int k0 = 0; k0 < DIM; k0 += 32) {
    if (isbf) {
      const unsigned short* X = (const unsigned short*)Xv;
      const unsigned short* E = (const unsigned short*)Ev;
      *(uint4*)(sA + flat0) = *(const uint4*)(X + iA0 + k0);
      *(uint4*)(sA + flat1) = *(const uint4*)(X + iA1 + k0);
      *(uint4*)(sB + flat0) = *(const uint4*)(E + iB0 + k0);
      *(uint4*)(sB + flat1) = *(const uint4*)(E + iB1 + k0);
    } else {
      const float* X = (const float*)Xv;
      const float* E = (const float*)Ev;
      *(u16x8*)(sA + flat0) = cvt8(X + iA0 + k0);
      *(u16x8*)(sA + flat1) = cvt8(X + iA1 + k0);
      *(u16x8*)(sB + flat0) = cvt8(E + iB0 + k0);
      *(u16x8*)(sB + flat1) = cvt8(E + iB1 + k0);
    }
    __syncthreads();

    bf16x8 a[4], b[4];
#pragma unroll
    for (int mt = 0; mt < 4; ++mt)
      a[mt] = *(const bf16x8*)(const void*)(sA + (wm * 64 + mt * 16 + l16) * 32 + quad * 8);
#pragma unroll
    for (int nt = 0; nt < 4; ++nt)
      b[nt] = *(const bf16x8*)(const void*)(sB + (wn * 64 + nt * 16 + l16) * 32 + quad * 8);
#pragma unroll
    for (int mt = 0; mt < 4; ++mt)
#pragma unroll
      for (int nt = 0; nt < 4; ++nt)
        acc[mt][nt] = __builtin_amdgcn_mfma_f32_16x16x32_bf16(a[mt], b[nt], acc[mt][nt], 0, 0, 0);
    __syncthreads();
  }

  float ec[4];
#pragma unroll
  for (int nt = 0; nt < 4; ++nt) ec[nt] = e2[colBase + wn * 64 + nt * 16 + l16];

  if (isbf) {
    unsigned short* out = (unsigned short*)outv;
#pragma unroll
    for (int mt = 0; mt < 4; ++mt)
#pragma unroll
      for (int r = 0; r < 4; ++r) {
        const int row = rowBase + wm * 64 + mt * 16 + quad * 4 + r;
        const float xr = x2[row];
#pragma unroll
        for (int nt = 0; nt < 4; ++nt) {
          const int col = colBase + wn * 64 + nt * 16 + l16;
          float sq = xr + ec[nt] - 2.0f * acc[mt][nt][r];
          sq = sq > 0.f ? sq : 0.f;
          out[(size_t)row * NGRP + col] = f2bf(-__builtin_sqrtf(sq));
        }
      }
  } else {
    float* out = (float*)outv;
#pragma unroll
    for (int mt = 0; mt < 4; ++mt)
#pragma unroll
      for (int r = 0; r < 4; ++r) {
        const int row = rowBase + wm * 64 + mt * 16 + quad * 4 + r;
        const float xr = x2[row];
#pragma unroll
        for (int nt = 0; nt < 4; ++nt) {
          const int col = colBase + wn * 64 + nt * 16 + l16;
          float sq = xr + ec[nt] - 2.0f * acc[mt][nt][r];
          sq = sq > 0.f ? sq : 0.f;
          out[(size_t)row * NGRP + col] = -__builtin_sqrtf(sq);
        }
      }
  }
}

extern "C" void kernel_launch(void* const* d_in, const int* in_sizes, int n_in,
                              void* d_out, int out_size, void* d_ws, size_t ws_size,
                              hipStream_t stream) {
  const size_t xbf = (size_t)NPTS * DIM;
  const size_t ebf = (size_t)NGRP * DIM;
  const size_t need = (xbf + ebf) * sizeof(unsigned short)
                    + (NPTS + NGRP) * sizeof(float) + 64;

  if (ws_size >= need) {
    // Fast path: fused prep (self-sniff) + 256^2 8-wave cross-barrier-pipelined GEMM.
    unsigned short* Xbf = (unsigned short*)d_ws;
    unsigned short* Ebf = Xbf + xbf;
    float* x2 = (float*)(Ebf + ebf);
    float* e2 = x2 + NPTS;

    prep_all_kernel<<<(NPTS + NGRP) / 4, 256, 0, stream>>>(d_in[0], d_in[1],
                                                           Xbf, Ebf, x2, e2);
    dim3 grid(NGRP / 256, NPTS / 256);
    gemm_8p_kernel<<<grid, 512, 0, stream>>>(d_in[0], Xbf, d_in[1], Ebf,
                                             x2, e2, d_out);
  } else {
    // Fallback: round-0 verified path.
    float* x2 = (float*)d_ws;
    float* e2 = x2 + NPTS;
    int* flag = (int*)(e2 + NGRP);

    sniff_kernel<<<1, 64, 0, stream>>>((const unsigned short*)d_in[0], flag);
    rownorm_kernel<<<NPTS / 4, 256, 0, stream>>>(d_in[0], x2, flag);
    rownorm_kernel<<<NGRP / 4, 256, 0, stream>>>(d_in[1], e2, flag);
    dim3 grid(NGRP / 128, NPTS / 128);
    gemm_dist_kernel<<<grid, 256, 0, stream>>>(d_in[0], d_in[1], x2, e2, d_out, flag);
  }
}

// Round 6
// 614.862 us; speedup vs baseline: 1.0191x; 1.0191x over previous
//
#include <hip/hip_runtime.h>
#include <hip/hip_bf16.h>

#define NPTS 16384
#define DIM  2048
#define NGRP 4096
#define BK   32
#define NT   (DIM / BK)   // 64 K-tiles

typedef __bf16 bf16x8 __attribute__((ext_vector_type(8)));
typedef unsigned short u16x8 __attribute__((ext_vector_type(8)));
typedef float f32x4 __attribute__((ext_vector_type(4)));
typedef long long i64f8;   // 8 packed fp8 (2 VGPR) — MFMA fp8 operand

__device__ __forceinline__ unsigned short f2bf(float f) {
  union { float f; unsigned u; } v; v.f = f;
  unsigned u = v.u;
  return (unsigned short)((u + 0x7FFFu + ((u >> 16) & 1u)) >> 16);  // RTNE
}
__device__ __forceinline__ float bflo(unsigned u) { return __uint_as_float(u << 16); }
__device__ __forceinline__ float bfhi(unsigned u) { return __uint_as_float(u & 0xffff0000u); }

// 4 floats -> 4 OCP e4m3 bytes (RNE, saturating) in one u32.
__device__ __forceinline__ unsigned cvtpk4(float a, float b, float c, float d) {
  int w = __builtin_amdgcn_cvt_pk_fp8_f32(a, b, 0, false);   // bytes 0,1
  w = __builtin_amdgcn_cvt_pk_fp8_f32(c, d, w, true);        // bytes 2,3
  return (unsigned)w;
}

// Async global->LDS, 16B per lane. LDS dest is wave-uniform base + lane*16.
__device__ __forceinline__ void gload16(const void* g, void* lds) {
  __builtin_amdgcn_global_load_lds(
      (const __attribute__((address_space(1))) unsigned*)g,
      (__attribute__((address_space(3))) unsigned*)lds, 16, 0, 0);
}

// Per-wave deterministic dtype sniff: all waves inspect X[0..63] -> identical verdict.
__device__ __forceinline__ bool sniff_bf16(const void* X) {
  const int lane = threadIdx.x & 63;
  unsigned hb = (((const unsigned short*)X)[lane] >> 8) & 0x7Fu;
  unsigned long long m = __ballot(hb >= 0x3Bu && hb <= 0x41u);
  return __popcll(m) >= 48;
}

// ---- fused prep: self-sniff + exact-fp32 row norms + fp8 e4m3 operand copy ----
// Norms stay exact (fp32 accumulation of the un-quantized values); only the GEMM
// cross term uses fp8, so d^2 error is the dot-product quantization alone.
__global__ __launch_bounds__(256) void prep_all_kernel(
    const void* __restrict__ Xin, const void* __restrict__ Ein,
    unsigned char* __restrict__ Xf8, unsigned char* __restrict__ Ef8,
    float* __restrict__ x2, float* __restrict__ e2) {
  const int lane  = threadIdx.x & 63;
  const int wavei = threadIdx.x >> 6;
  const bool isbf = sniff_bf16(Xin);

  const int grow = blockIdx.x * 4 + wavei;
  const void* in; unsigned char* q; float* nrm; int row;
  if (grow < NPTS) { in = Xin; q = Xf8; nrm = x2; row = grow; }
  else             { in = Ein; q = Ef8; nrm = e2; row = grow - NPTS; }

  unsigned char* qq = q + (size_t)row * DIM;
  float s = 0.f;
#pragma unroll
  for (int it = 0; it < 4; ++it) {
    float v0, v1, v2, v3, v4, v5, v6, v7;
    if (isbf) {
      const unsigned short* p = (const unsigned short*)in + (size_t)row * DIM;
      uint4 r = *(const uint4*)(p + it * 512 + lane * 8);
      v0 = bflo(r.x); v1 = bfhi(r.x); v2 = bflo(r.y); v3 = bfhi(r.y);
      v4 = bflo(r.z); v5 = bfhi(r.z); v6 = bflo(r.w); v7 = bfhi(r.w);
    } else {
      const float* p = (const float*)in + (size_t)row * DIM;
      float4 a = *(const float4*)(p + it * 512 + lane * 8);
      float4 b = *(const float4*)(p + it * 512 + lane * 8 + 4);
      v0 = a.x; v1 = a.y; v2 = a.z; v3 = a.w;
      v4 = b.x; v5 = b.y; v6 = b.z; v7 = b.w;
    }
    s += v0 * v0 + v1 * v1 + v2 * v2 + v3 * v3;
    s += v4 * v4 + v5 * v5 + v6 * v6 + v7 * v7;
    uint2 w;
    w.x = cvtpk4(v0, v1, v2, v3);
    w.y = cvtpk4(v4, v5, v6, v7);
    *(uint2*)(qq + it * 512 + lane * 8) = w;
  }
#pragma unroll
  for (int off = 32; off > 0; off >>= 1) s += __shfl_down(s, off, 64);
  if (lane == 0) nrm[row] = s;
}

// ---- 256x256 8-wave fp8 GEMM, BK=32, 4-deep circular LDS (64 KiB).
//      One barrier/tile. Schedule per tile t:
//        vmcnt(2) [t+1 landed] + barrier -> STAGE(t+3) -> DSR(t+1, alt regs)
//        -> lgkmcnt(12) [only tile-t's 12 reads] -> 32 MFMA.
//      Next-tile ds_read latency drains under the MFMA cluster; staging and
//      frag reads double-buffered in named register sets (rule #20). ----
__global__ __launch_bounds__(512, 2) void gemm_f8_kernel(
    const void* __restrict__ Xin,            // output-dtype sniff only
    const unsigned char* __restrict__ X8, const unsigned char* __restrict__ E8,
    const float* __restrict__ x2, const float* __restrict__ e2,
    void* __restrict__ outv) {
  // 4 bufs x [ A: 256x32 fp8 (8KB) | B: 256x32 fp8 (8KB) ] = 64 KiB
  __shared__ __align__(16) unsigned char sbuf[4][16384];

  const int tid  = threadIdx.x;
  const int lane = tid & 63;
  const int wave = tid >> 6;   // 0..7
  const int wm   = wave >> 2;  // 0..1  (M half: 128 rows)
  const int wn   = wave & 3;   // 0..3  (N quarter: 64 cols)
  const int quad = lane >> 4;
  const int l16  = lane & 15;

  const bool isbf = sniff_bf16(Xin);

  const int rowBase = blockIdx.y * 256;
  const int colBase = blockIdx.x * 256;

  // Staging: ONE gload16 per operand per tile moves the full 256x32 fp8 tile
  // (512 thr x 16 B = 8 KB). Thread t: row = t>>1, byte-col = (t&1)*16.
  const size_t gA = (size_t)(rowBase + (tid >> 1)) * DIM + (tid & 1) * 16;
  const size_t gB = (size_t)(colBase + (tid >> 1)) * DIM + (tid & 1) * 16;

  // Fragment byte offsets. A frag mt: row = wm*128 + mt*16 + l16, k = quad*8.
  // b64 reads: 4 lanes share each bank-pair -> LDS pipe floor, no swizzle needed.
  const int aoff = (wm * 128 + l16) * 32 + quad * 8;          // + mt*512
  const int boff = 8192 + (wn * 64 + l16) * 32 + quad * 8;    // + nt*512

  f32x4 zero = {0.f, 0.f, 0.f, 0.f};
  f32x4 acc[8][4];
#pragma unroll
  for (int mt = 0; mt < 8; ++mt)
#pragma unroll
    for (int nt = 0; nt < 4; ++nt) acc[mt][nt] = zero;

  i64f8 a0[8], b0[4], a1[8], b1[4];   // double-buffered fragment sets

#define STAGE(t_) do {                                                          \
    gload16(X8 + gA + (size_t)(t_) * BK, &sbuf[(t_) & 3][wave * 1024]);         \
    gload16(E8 + gB + (size_t)(t_) * BK, &sbuf[(t_) & 3][8192 + wave * 1024]);  \
  } while (0)

#define DSR(t_, A_, B_) do { const unsigned char* sb_ = sbuf[(t_) & 3];         \
    _Pragma("unroll") for (int mt = 0; mt < 8; ++mt)                            \
      A_[mt] = *(const i64f8*)(const void*)(sb_ + aoff + mt * 512);             \
    _Pragma("unroll") for (int nt = 0; nt < 4; ++nt)                            \
      B_[nt] = *(const i64f8*)(const void*)(sb_ + boff + nt * 512);             \
  } while (0)

#define MFMA32(A_, B_) do {                                                     \
    __builtin_amdgcn_s_setprio(1);                                              \
    _Pragma("unroll") for (int mt = 0; mt < 8; ++mt)                            \
      _Pragma("unroll") for (int nt = 0; nt < 4; ++nt)                          \
        acc[mt][nt] = __builtin_amdgcn_mfma_f32_16x16x32_fp8_fp8(               \
            A_[mt], B_[nt], acc[mt][nt], 0, 0, 0);                              \
    __builtin_amdgcn_s_setprio(0);                                              \
    asm volatile("" ::: "memory");                                              \
  } while (0)

  // Race audit: STAGE(t+3) writes buf[(t-1)&3] AFTER the tile-t barrier; every
  // wave's reads of buf t-1 completed at its lgkmcnt wait in tile t-1, which
  // precedes its tile-t barrier arrival. DSR(t+1) reads only after each wave's
  // own vmcnt(2) (t+1 stores landed) + the shared barrier.
#define BODY(t_, DOSTAGE_, VMS_, A_, B_, DONEXT_, AN_, BN_, LKS_) do {          \
    asm volatile("s_waitcnt vmcnt(" VMS_ ")" ::: "memory");                     \
    __builtin_amdgcn_s_barrier();                                               \
    __builtin_amdgcn_sched_barrier(0);                                          \
    if (DOSTAGE_) STAGE((t_) + 3);                                              \
    if (DONEXT_) DSR((t_) + 1, AN_, BN_);                                       \
    __builtin_amdgcn_sched_barrier(0);                                          \
    asm volatile("s_waitcnt lgkmcnt(" LKS_ ")" ::: "memory");                   \
    __builtin_amdgcn_sched_barrier(0);                                          \
    MFMA32(A_, B_);                                                             \
  } while (0)

  // Prologue: 3 tiles in flight (6 loads/thread); tile 0 resident; frags of 0.
  STAGE(0); STAGE(1); STAGE(2);
  asm volatile("s_waitcnt vmcnt(4)" ::: "memory");
  __builtin_amdgcn_s_barrier();
  __builtin_amdgcn_sched_barrier(0);
  DSR(0, a0, b0);
  __builtin_amdgcn_sched_barrier(0);

  // Main pairs (tile t uses set t&1; fills set (t+1)&1).
#pragma unroll 1
  for (int p = 0; p < 29; ++p) {
    const int t = 2 * p;
    BODY(t,     true, "2", a0, b0, true, a1, b1, "12");
    BODY(t + 1, true, "2", a1, b1, true, a0, b0, "12");
  }
  // Peeled tail: stages 61,62,63 then drain (vmcnt 2 -> 2 -> 0 -> 0).
  BODY(58, true,  "2", a0, b0, true, a1, b1, "12");
  BODY(59, true,  "2", a1, b1, true, a0, b0, "12");
  BODY(60, true,  "2", a0, b0, true, a1, b1, "12");
  BODY(61, false, "2", a1, b1, true, a0, b0, "12");
  BODY(62, false, "0", a0, b0, true, a1, b1, "12");
  BODY(63, false, "0", a1, b1, false, a0, b0, "0");
#undef BODY
#undef MFMA32
#undef DSR
#undef STAGE

  // Epilogue. C/D layout: col = lane&15, row = quad*4 + reg (dtype-independent).
  float ec[4];
#pragma unroll
  for (int nt = 0; nt < 4; ++nt) ec[nt] = e2[colBase + wn * 64 + nt * 16 + l16];

  if (isbf) {
    unsigned short* out = (unsigned short*)outv;
#pragma unroll
    for (int mt = 0; mt < 8; ++mt)
#pragma unroll
      for (int r2 = 0; r2 < 4; ++r2) {
        const int row = rowBase + wm * 128 + mt * 16 + quad * 4 + r2;
        const float xr = x2[row];
#pragma unroll
        for (int nt = 0; nt < 4; ++nt) {
          const int col = colBase + wn * 64 + nt * 16 + l16;
          float sq = xr + ec[nt] - 2.0f * acc[mt][nt][r2];
          sq = sq > 0.f ? sq : 0.f;
          out[(size_t)row * NGRP + col] = f2bf(-__builtin_sqrtf(sq));
        }
      }
  } else {
    float* out = (float*)outv;
#pragma unroll
    for (int mt = 0; mt < 8; ++mt)
#pragma unroll
      for (int r2 = 0; r2 < 4; ++r2) {
        const int row = rowBase + wm * 128 + mt * 16 + quad * 4 + r2;
        const float xr = x2[row];
#pragma unroll
        for (int nt = 0; nt < 4; ++nt) {
          const int col = colBase + wn * 64 + nt * 16 + l16;
          float sq = xr + ec[nt] - 2.0f * acc[mt][nt][r2];
          sq = sq > 0.f ? sq : 0.f;
          out[(size_t)row * NGRP + col] = -__builtin_sqrtf(sq);
        }
      }
  }
}

// ---------------- fallback path (workspace too small): round-0 kernels ----------------

__global__ void sniff_kernel(const unsigned short* __restrict__ X, int* __restrict__ flag) {
  if (threadIdx.x == 0 && blockIdx.x == 0) {
    int c = 0;
    for (int i = 0; i < 64; ++i) {
      unsigned b = (X[i] >> 8) & 0x7F;
      c += (b >= 0x3B && b <= 0x41) ? 1 : 0;
    }
    *flag = (c >= 48) ? 1 : 0;
  }
}

__global__ __launch_bounds__(256) void rownorm_kernel(const void* __restrict__ in,
                                                      float* __restrict__ out,
                                                      const int* __restrict__ flag) {
  const int wave = threadIdx.x >> 6;
  const int lane = threadIdx.x & 63;
  const int row  = blockIdx.x * 4 + wave;
  float s = 0.f;
  if (*flag) {
    const unsigned short* p = (const unsigned short*)in + (size_t)row * DIM;
#pragma unroll
    for (int it = 0; it < 4; ++it) {
      uint4 v = *(const uint4*)(p + it * 512 + lane * 8);
      float f;
      f = bflo(v.x); s += f * f;  f = bfhi(v.x); s += f * f;
      f = bflo(v.y); s += f * f;  f = bfhi(v.y); s += f * f;
      f = bflo(v.z); s += f * f;  f = bfhi(v.z); s += f * f;
      f = bflo(v.w); s += f * f;  f = bfhi(v.w); s += f * f;
    }
  } else {
    const float* p = (const float*)in + (size_t)row * DIM;
#pragma unroll
    for (int it = 0; it < 4; ++it) {
      float4 a = *(const float4*)(p + it * 512 + lane * 8);
      float4 b = *(const float4*)(p + it * 512 + lane * 8 + 4);
      s += a.x * a.x + a.y * a.y + a.z * a.z + a.w * a.w;
      s += b.x * b.x + b.y * b.y + b.z * b.z + b.w * b.w;
    }
  }
#pragma unroll
  for (int off = 32; off > 0; off >>= 1) s += __shfl_down(s, off, 64);
  if (lane == 0) out[row] = s;
}

__device__ __forceinline__ u16x8 cvt8(const float* p) {
  float4 a = *(const float4*)p;
  float4 b = *(const float4*)(p + 4);
  u16x8 r;
  r[0] = f2bf(a.x); r[1] = f2bf(a.y); r[2] = f2bf(a.z); r[3] = f2bf(a.w);
  r[4] = f2bf(b.x); r[5] = f2bf(b.y); r[6] = f2bf(b.z); r[7] = f2bf(b.w);
  return r;
}

__global__ __launch_bounds__(256) void gemm_dist_kernel(
    const void* __restrict__ Xv, const void* __restrict__ Ev,
    const float* __restrict__ x2, const float* __restrict__ e2,
    void* __restrict__ outv, const int* __restrict__ flag) {
  __shared__ __align__(16) unsigned short sA[128 * 32];
  __shared__ __align__(16) unsigned short sB[128 * 32];

  const bool isbf = (*flag != 0);
  const int tid  = threadIdx.x;
  const int lane = tid & 63;
  const int wave = tid >> 6;
  const int wm   = wave >> 1;
  const int wn   = wave & 1;
  const int quad = lane >> 4;
  const int l16  = lane & 15;

  const int rowBase = blockIdx.y * 128;
  const int colBase = blockIdx.x * 128;

  const int flat0 = tid * 8;
  const int flat1 = (tid + 256) * 8;
  const int r0 = flat0 >> 5, c0 = flat0 & 31;
  const int r1 = flat1 >> 5, c1 = flat1 & 31;

  const size_t iA0 = (size_t)(rowBase + r0) * DIM + c0;
  const size_t iA1 = (size_t)(rowBase + r1) * DIM + c1;
  const size_t iB0 = (size_t)(colBase + r0) * DIM + c0;
  const size_t iB1 = (size_t)(colBase + r1) * DIM + c1;

  f32x4 zero = {0.f, 0.f, 0.f, 0.f};
  f32x4 acc[4][4];
#pragma unroll
  for (int mt = 0; mt < 4; ++mt)
#pragma unroll
    for (int nt = 0; nt < 4; ++nt) acc[mt][nt] = zero;

  for (int k0 = 0; k0 < DIM; k0 += 32) {
    if (isbf) {
      const unsigned short* X = (const unsigned short*)Xv;
      const unsigned short* E = (const unsigned short*)Ev;
      *(uint4*)(sA + flat0) = *(const uint4*)(X + iA0 + k0);
      *(uint4*)(sA + flat1) = *(const uint4*)(X + iA1 + k0);
      *(uint4*)(sB + flat0) = *(const uint4*)(E + iB0 + k0);
      *(uint4*)(sB + flat1) = *(const uint4*)(E + iB1 + k0);
    } else {
      const float* X = (const float*)Xv;
      const float* E = (const float*)Ev;
      *(u16x8*)(sA + flat0) = cvt8(X + iA0 + k0);
      *(u16x8*)(sA + flat1) = cvt8(X + iA1 + k0);
      *(u16x8*)(sB + flat0) = cvt8(E + iB0 + k0);
      *(u16x8*)(sB + flat1) = cvt8(E + iB1 + k0);
    }
    __syncthreads();

    bf16x8 a[4], b[4];
#pragma unroll
    for (int mt = 0; mt < 4; ++mt)
      a[mt] = *(const bf16x8*)(const void*)(sA + (wm * 64 + mt * 16 + l16) * 32 + quad * 8);
#pragma unroll
    for (int nt = 0; nt < 4; ++nt)
      b[nt] = *(const bf16x8*)(const void*)(sB + (wn * 64 + nt * 16 + l16) * 32 + quad * 8);
#pragma unroll
    for (int mt = 0; mt < 4; ++mt)
#pragma unroll
      for (int nt = 0; nt < 4; ++nt)
        acc[mt][nt] = __builtin_amdgcn_mfma_f32_16x16x32_bf16(a[mt], b[nt], acc[mt][nt], 0, 0, 0);
    __syncthreads();
  }

  float ec[4];
#pragma unroll
  for (int nt = 0; nt < 4; ++nt) ec[nt] = e2[colBase + wn * 64 + nt * 16 + l16];

  if (isbf) {
    unsigned short* out = (unsigned short*)outv;
#pragma unroll
    for (int mt = 0; mt < 4; ++mt)
#pragma unroll
      for (int r = 0; r < 4; ++r) {
        const int row = rowBase + wm * 64 + mt * 16 + quad * 4 + r;
        const float xr = x2[row];
#pragma unroll
        for (int nt = 0; nt < 4; ++nt) {
          const int col = colBase + wn * 64 + nt * 16 + l16;
          float sq = xr + ec[nt] - 2.0f * acc[mt][nt][r];
          sq = sq > 0.f ? sq : 0.f;
          out[(size_t)row * NGRP + col] = f2bf(-__builtin_sqrtf(sq));
        }
      }
  } else {
    float* out = (float*)outv;
#pragma unroll
    for (int mt = 0; mt < 4; ++mt)
#pragma unroll
      for (int r = 0; r < 4; ++r) {
        const int row = rowBase + wm * 64 + mt * 16 + quad * 4 + r;
        const float xr = x2[row];
#pragma unroll
        for (int nt = 0; nt < 4; ++nt) {
          const int col = colBase + wn * 64 + nt * 16 + l16;
          float sq = xr + ec[nt] - 2.0f * acc[mt][nt][r];
          sq = sq > 0.f ? sq : 0.f;
          out[(size_t)row * NGRP + col] = -__builtin_sqrtf(sq);
        }
      }
  }
}

extern "C" void kernel_launch(void* const* d_in, const int* in_sizes, int n_in,
                              void* d_out, int out_size, void* d_ws, size_t ws_size,
                              hipStream_t stream) {
  const size_t xf8 = (size_t)NPTS * DIM;
  const size_t ef8 = (size_t)NGRP * DIM;
  const size_t need = xf8 + ef8 + (NPTS + NGRP) * sizeof(float) + 64;

  if (ws_size >= need) {
    // Fast path: fused prep (exact norms + fp8 copy) + fp8 pipelined GEMM.
    unsigned char* Xf8 = (unsigned char*)d_ws;
    unsigned char* Ef8 = Xf8 + xf8;
    float* x2 = (float*)(Ef8 + ef8);
    float* e2 = x2 + NPTS;

    prep_all_kernel<<<(NPTS + NGRP) / 4, 256, 0, stream>>>(d_in[0], d_in[1],
                                                           Xf8, Ef8, x2, e2);
    dim3 grid(NGRP / 256, NPTS / 256);
    gemm_f8_kernel<<<grid, 512, 0, stream>>>(d_in[0], Xf8, Ef8, x2, e2, d_out);
  } else {
    // Fallback: round-0 verified bf16 path.
    float* x2 = (float*)d_ws;
    float* e2 = x2 + NPTS;
    int* flag = (int*)(e2 + NGRP);

    sniff_kernel<<<1, 64, 0, stream>>>((const unsigned short*)d_in[0], flag);
    rownorm_kernel<<<NPTS / 4, 256, 0, stream>>>(d_in[0], x2, flag);
    rownorm_kernel<<<NGRP / 4, 256, 0, stream>>>(d_in[1], e2, flag);
    dim3 grid(NGRP / 128, NPTS / 128);
    gemm_dist_kernel<<<grid, 256, 0, stream>>>(d_in[0], d_in[1], x2, e2, d_out, flag);
  }
}